// Round 1
// 323.953 us; speedup vs baseline: 1.0256x; 1.0256x over previous
//
#include <hip/hip_runtime.h>
#include <hip/hip_bf16.h>

namespace {

typedef __attribute__((ext_vector_type(8))) short bf16x8;   // 8 bf16 = 4 VGPRs
typedef __attribute__((ext_vector_type(4))) float f32x4;
typedef __attribute__((ext_vector_type(4))) unsigned u32x4v;

constexpr int BATCH = 4;
constexpr int SEQ   = 2048;
constexpr int EMB   = 1024;
constexpr int NH    = 16;
constexpr int HD    = 64;
constexpr int MTOT  = BATCH * SEQ;           // 8192
constexpr int KVW   = 2 * EMB;               // fused K|V row width (2048)
constexpr float LOG2E = 1.44269504088896f;
constexpr float SOFTMAX_C = 16.0f;           // static max substitute (log2 units)

__device__ __forceinline__ unsigned short f2bf(float x) {
    unsigned int u = __float_as_uint(x);
    u += 0x7fffu + ((u >> 16) & 1u);         // round-to-nearest-even
    return (unsigned short)(u >> 16);
}

// async global->LDS, 16B per lane; LDS dest must be wave-uniform base + lane*16
__device__ __forceinline__ void gl_lds16(const void* g, void* l) {
    __builtin_amdgcn_global_load_lds(
        (const __attribute__((address_space(1))) unsigned int*)g,
        (__attribute__((address_space(3))) unsigned int*)l, 16, 0, 0);
}

// ---------------------------------------------------------------------------
// fp32 -> bf16 for dec (y=0) and enc (y=1) in one launch
// ---------------------------------------------------------------------------
__global__ __launch_bounds__(256)
void conv_bf16(const float* __restrict__ dec, const float* __restrict__ enc,
               unsigned short* __restrict__ decb, unsigned short* __restrict__ encb,
               int n4)
{
    int i = blockIdx.x * 256 + threadIdx.x;
    if (i >= n4) return;
    const float* src = blockIdx.y ? enc : dec;
    unsigned short* dst = blockIdx.y ? encb : decb;
    float4 v = ((const float4*)src)[i];
    ushort4 o;
    o.x = f2bf(v.x); o.y = f2bf(v.y); o.z = f2bf(v.z); o.w = f2bf(v.w);
    ((ushort4*)dst)[i] = o;
}

// ---------------------------------------------------------------------------
// All four weights: W[K][N] fp32 -> Wt[N][K] bf16 (×scale for z=0).
// ---------------------------------------------------------------------------
__global__ __launch_bounds__(256)
void wtrans(const float* __restrict__ W0, const float* __restrict__ W1,
            const float* __restrict__ W2, const float* __restrict__ W3,
            unsigned short* __restrict__ WtBase, float qscale)
{
    __shared__ __align__(16) unsigned short Ts[64][65];
    const int tid = threadIdx.x;
    const int z = blockIdx.z;
    const float* W = (z == 0) ? W0 : (z == 1) ? W1 : (z == 2) ? W2 : W3;
    unsigned short* Wt = WtBase + (size_t)z * EMB * EMB;
    const float scale = (z == 0) ? qscale : 1.0f;
    const int n0 = blockIdx.x * 64, k0 = blockIdx.y * 64;
    #pragma unroll
    for (int i = 0; i < 4; ++i) {
        int id = tid + i * 256;
        int r = id >> 4, q = id & 15;
        float4 v = *(const float4*)&W[(size_t)(k0 + r) * EMB + n0 + q * 4];
        Ts[q * 4 + 0][r] = f2bf(v.x * scale);
        Ts[q * 4 + 1][r] = f2bf(v.y * scale);
        Ts[q * 4 + 2][r] = f2bf(v.z * scale);
        Ts[q * 4 + 3][r] = f2bf(v.w * scale);
    }
    __syncthreads();
    #pragma unroll
    for (int i = 0; i < 4; ++i) {
        int id = tid + i * 256;
        int rn = id >> 4, q = id & 15;
        ushort4 o;
        o.x = Ts[rn][q * 4 + 0]; o.y = Ts[rn][q * 4 + 1];
        o.z = Ts[rn][q * 4 + 2]; o.w = Ts[rn][q * 4 + 3];
        *(ushort4*)&Wt[(size_t)(n0 + rn) * EMB + k0 + q * 4] = o;
    }
}

// ---------------------------------------------------------------------------
// V (cols 1024.. of KVb, row stride KVW) -> Vt[(b*16+h)*64 + d][S] bf16.
// KEY PERMUTATION: within each 32-key group, 4-key chunks are stored in order
// [0,4,1,5,2,6,3,7] so that the attn PV MFMA's A-fragment (built in-register
// from the S^T output: lane g owns keys {kt*16+4g..+4}) matches the B-operand
// k-slot mapping with NO cross-lane data movement. Sum over k is permutation-
// invariant, so the result is exact.
// ---------------------------------------------------------------------------
__global__ __launch_bounds__(256)
void vtrans(const unsigned short* __restrict__ V, unsigned short* __restrict__ Vt)
{
    __shared__ __align__(16) unsigned short Ts[64][72];
    const int tid = threadIdx.x;
    const int s0 = blockIdx.x * 64;
    const int bh = blockIdx.y, b = bh >> 4, h = bh & 15;
    #pragma unroll
    for (int it = 0; it < 2; ++it) {
        int id = tid + it * 256;
        int r = id >> 3, seg = id & 7;
        uint4 v = *(const uint4*)&V[(size_t)(b * SEQ + s0 + r) * KVW + h * HD + seg * 8];
        const unsigned short* pv = (const unsigned short*)&v;
        #pragma unroll
        for (int j = 0; j < 8; ++j) Ts[seg * 8 + j][r] = pv[j];
    }
    __syncthreads();
    #pragma unroll
    for (int it = 0; it < 2; ++it) {
        int id = tid + it * 256;
        int d = id >> 3, sg = id & 7;
        // position chunk pair (2t,2t+1) <- source chunks (t, 4+t) within 32-key group
        int base = (sg >> 2) * 32 + (sg & 3) * 4;
        uint2 wlo = *(const uint2*)&Ts[d][base];
        uint2 whi = *(const uint2*)&Ts[d][base + 16];
        uint4 w;
        w.x = wlo.x; w.y = wlo.y; w.z = whi.x; w.w = whi.y;
        *(uint4*)&Vt[((size_t)bh * HD + d) * SEQ + s0 + sg * 8] = w;
    }
}

// ---------------------------------------------------------------------------
// Pipelined GEMM body: C[M,N] = A[M,K] @ Bt[N,K]^T (+bias). 128x128 tile,
// BK=32, DOUBLE-buffered LDS + global_load_lds.
// ---------------------------------------------------------------------------
template<bool OUT_BF16, bool BIAS>
__device__ __forceinline__
void gemm_body(const unsigned short* __restrict__ A, const unsigned short* __restrict__ Bt,
               const float* __restrict__ bias, void* __restrict__ Cout,
               int m0, int n0, int N, int Kd)
{
    __shared__ __align__(16) unsigned short As[2][128 * 32];
    __shared__ __align__(16) unsigned short Bs[2][128 * 32];
    const int tid  = threadIdx.x;
    const int lane = tid & 63, wave = tid >> 6;
    const int g = lane >> 4, c = lane & 15;
    const int wm = (wave & 1) * 64, wn = (wave >> 1) * 64;

    const int r0 = tid >> 2, s = tid & 3;
    const int sg = s ^ ((r0 + (r0 >> 2)) & 3);
    const unsigned short* ga0 = A  + (size_t)(m0 + r0)      * Kd + sg * 8;
    const unsigned short* ga1 = A  + (size_t)(m0 + r0 + 64) * Kd + sg * 8;
    const unsigned short* gb0 = Bt + (size_t)(n0 + r0)      * Kd + sg * 8;
    const unsigned short* gb1 = Bt + (size_t)(n0 + r0 + 64) * Kd + sg * 8;
    const int lo0 = tid * 8, lo1 = (256 + tid) * 8;

    const int cs = (c + (c >> 2)) & 3;

    f32x4 acc[4][4];
    #pragma unroll
    for (int i = 0; i < 4; ++i)
        #pragma unroll
        for (int j = 0; j < 4; ++j) acc[i][j] = (f32x4)0.0f;

    // prologue: tile 0 -> buf0
    gl_lds16(ga0, &As[0][lo0]); gl_lds16(ga1, &As[0][lo1]);
    gl_lds16(gb0, &Bs[0][lo0]); gl_lds16(gb1, &Bs[0][lo1]);
    ga0 += 32; ga1 += 32; gb0 += 32; gb1 += 32;
    __syncthreads();

    const int KT = Kd / 32;                      // even
    for (int kt = 0; kt < KT; kt += 2) {
        #pragma unroll
        for (int h2 = 0; h2 < 2; ++h2) {         // h2 = buffer parity (constant)
            const int k = kt + h2;
            if (k + 1 < KT) {                    // issue next tile early (async)
                gl_lds16(ga0, &As[h2 ^ 1][lo0]); gl_lds16(ga1, &As[h2 ^ 1][lo1]);
                gl_lds16(gb0, &Bs[h2 ^ 1][lo0]); gl_lds16(gb1, &Bs[h2 ^ 1][lo1]);
                ga0 += 32; ga1 += 32; gb0 += 32; gb1 += 32;
            }
            bf16x8 af[4], bfr[4];
            #pragma unroll
            for (int mt = 0; mt < 4; ++mt)
                af[mt]  = *(const bf16x8*)&As[h2][(wm + mt * 16 + c) * 32 + (g ^ cs) * 8];
            #pragma unroll
            for (int nt = 0; nt < 4; ++nt)
                bfr[nt] = *(const bf16x8*)&Bs[h2][(wn + nt * 16 + c) * 32 + (g ^ cs) * 8];
            #pragma unroll
            for (int mt = 0; mt < 4; ++mt)
                #pragma unroll
                for (int nt = 0; nt < 4; ++nt)
                    acc[mt][nt] = __builtin_amdgcn_mfma_f32_16x16x32_bf16(af[mt], bfr[nt], acc[mt][nt], 0, 0, 0);
            __syncthreads();                     // drain lands post-compute
        }
    }

    #pragma unroll
    for (int mt = 0; mt < 4; ++mt) {
        #pragma unroll
        for (int nt = 0; nt < 4; ++nt) {
            int n = n0 + wn + nt * 16 + c;
            float bv = BIAS ? bias[n] : 0.0f;
            #pragma unroll
            for (int r = 0; r < 4; ++r) {
                int m = m0 + wm + mt * 16 + 4 * g + r;
                float v = acc[mt][nt][r] + bv;
                if (OUT_BF16) ((unsigned short*)Cout)[(size_t)m * N + n] = f2bf(v);
                else          ((float*)Cout)[(size_t)m * N + n] = v;
            }
        }
    }
}

// Fused Q + KV projections: grid.x = 24 n-tiles (0..7 -> Q, 8..23 -> K|V)
__global__ __launch_bounds__(256)
void proj_fused(const unsigned short* __restrict__ decb, const unsigned short* __restrict__ encb,
                const unsigned short* __restrict__ WtBase,
                unsigned short* __restrict__ Qb, unsigned short* __restrict__ KVb)
{
    const int nt = blockIdx.x;
    const int m0 = blockIdx.y * 128;
    if (nt < 8) {
        gemm_body<true, false>(decb, WtBase, nullptr, Qb, m0, nt * 128, EMB, EMB);
    } else {
        gemm_body<true, false>(encb, WtBase + (size_t)EMB * EMB, nullptr, KVb,
                               m0, (nt - 8) * 128, KVW, EMB);
    }
}

// Out projection (fp32 out + bias)
__global__ __launch_bounds__(256)
void proj_out(const unsigned short* __restrict__ Ob, const unsigned short* __restrict__ WoT,
              const float* __restrict__ bo, float* __restrict__ out)
{
    gemm_body<false, true>(Ob, WoT, bo, out, blockIdx.y * 128, blockIdx.x * 128, EMB, EMB);
}

// ---------------------------------------------------------------------------
// MFMA flash attention, S^T formulation, static max folded into MFMA C-init.
// P never touches LDS: the S^T MFMA output (lane c,g holds P[q=c][kt*16+4g+r],
// kt=0..3) is packed with v_cvt_pk_bf16_f32 and used DIRECTLY as the PV
// A-fragment under a permuted MFMA-k <-> key mapping; Vt carries the matching
// key permutation (see vtrans). LDS = 32 KB (K/V double buffers only) ->
// 5 blocks/CU, whole grid resident.
// ---------------------------------------------------------------------------
__global__ __launch_bounds__(256)
void attn(const unsigned short* __restrict__ Q, const unsigned short* __restrict__ KV,
          const unsigned short* __restrict__ Vt, unsigned short* __restrict__ O)
{
    __shared__ __align__(16) unsigned short Ks[2][64 * 64];  // [key][d], seg^(row&7)
    __shared__ __align__(16) unsigned short Vs[2][64 * 64];  // [d][key], seg^(row&7)

    const int tid  = threadIdx.x;
    const int lane = tid & 63, wave = tid >> 6;
    const int g = lane >> 4, c = lane & 15, c7 = c & 7;
    const int bh = blockIdx.y, b = bh >> 4, h = bh & 15;
    const int qw = blockIdx.x * 128 + wave * 32;

    const unsigned short* Qp0 = Q + (size_t)(b * SEQ + qw + c) * EMB + h * HD;
    const unsigned short* Qp1 = Qp0 + (size_t)16 * EMB;
    bf16x8 qb[2][2];
    qb[0][0] = *(const bf16x8*)(Qp0 + g * 8);
    qb[0][1] = *(const bf16x8*)(Qp0 + 32 + g * 8);
    qb[1][0] = *(const bf16x8*)(Qp1 + g * 8);
    qb[1][1] = *(const bf16x8*)(Qp1 + 32 + g * 8);

    const int r0 = tid >> 3, s8 = tid & 7;
    const int sg = s8 ^ (r0 & 7);
    const unsigned short* gK0 = KV + ((size_t)b * SEQ + r0) * KVW + h * HD + sg * 8;
    const unsigned short* gK1 = gK0 + (size_t)32 * KVW;
    const unsigned short* gV0 = Vt + (size_t)bh * HD * SEQ + (size_t)r0 * SEQ + sg * 8;
    const unsigned short* gV1 = gV0 + (size_t)32 * SEQ;
    const int lo0 = tid * 8, lo1 = (256 + tid) * 8;

    f32x4 oac[2][4];
    #pragma unroll
    for (int bd = 0; bd < 2; ++bd)
        #pragma unroll
        for (int dt = 0; dt < 4; ++dt) oac[bd][dt] = (f32x4)0.0f;
    float lrun[2] = {0.0f, 0.0f};
    const f32x4 minit = {-SOFTMAX_C, -SOFTMAX_C, -SOFTMAX_C, -SOFTMAX_C};

    // prologue: tile 0 -> buf0
    gl_lds16(gK0, &Ks[0][lo0]); gl_lds16(gK1, &Ks[0][lo1]);
    gl_lds16(gV0, &Vs[0][lo0]); gl_lds16(gV1, &Vs[0][lo1]);
    gK0 += (size_t)64 * KVW; gK1 += (size_t)64 * KVW; gV0 += 64; gV1 += 64;
    __syncthreads();

    constexpr int T = SEQ / 64;                  // 32, even
    for (int t = 0; t < T; t += 2) {
        #pragma unroll
        for (int h2 = 0; h2 < 2; ++h2) {         // h2 = buffer parity (constant)
            const int tt = t + h2;
            if (tt + 1 < T) {                    // issue next K/V tile early
                gl_lds16(gK0, &Ks[h2 ^ 1][lo0]); gl_lds16(gK1, &Ks[h2 ^ 1][lo1]);
                gl_lds16(gV0, &Vs[h2 ^ 1][lo0]); gl_lds16(gV1, &Vs[h2 ^ 1][lo1]);
                gK0 += (size_t)64 * KVW; gK1 += (size_t)64 * KVW;
                gV0 += 64;               gV1 += 64;
            }

            // S^T = K Q^T, C-init = -C (softmax shift folded in)
            f32x4 st[2][4];
            #pragma unroll
            for (int kt = 0; kt < 4; ++kt) {
                bf16x8 ka0 = *(const bf16x8*)&Ks[h2][(kt * 16 + c) * 64 + (g ^ c7) * 8];
                bf16x8 ka1 = *(const bf16x8*)&Ks[h2][(kt * 16 + c) * 64 + ((4 + g) ^ c7) * 8];
                #pragma unroll
                for (int bd = 0; bd < 2; ++bd) {
                    st[bd][kt] = __builtin_amdgcn_mfma_f32_16x16x32_bf16(ka0, qb[bd][0], minit, 0, 0, 0);
                    st[bd][kt] = __builtin_amdgcn_mfma_f32_16x16x32_bf16(ka1, qb[bd][1], st[bd][kt], 0, 0, 0);
                }
            }

            // p = exp2(st); accumulate l; pack in-register (v_cvt_pk_bf16_f32).
            // Lane (c,g) ends up holding P[q][keys 4g..4g+4 and 16+4g..+4] per
            // 32-key half — exactly the PV A-fragment under the permuted k-map.
            bf16x8 pa[2][2];
            #pragma unroll
            for (int bd = 0; bd < 2; ++bd) {
                float ls = lrun[bd];
                unsigned uu[8];
                #pragma unroll
                for (int kt = 0; kt < 4; ++kt) {
                    float p0 = __builtin_amdgcn_exp2f(st[bd][kt][0]);
                    float p1 = __builtin_amdgcn_exp2f(st[bd][kt][1]);
                    float p2 = __builtin_amdgcn_exp2f(st[bd][kt][2]);
                    float p3 = __builtin_amdgcn_exp2f(st[bd][kt][3]);
                    ls += (p0 + p1) + (p2 + p3);
                    asm("v_cvt_pk_bf16_f32 %0, %1, %2" : "=v"(uu[2 * kt])     : "v"(p0), "v"(p1));
                    asm("v_cvt_pk_bf16_f32 %0, %1, %2" : "=v"(uu[2 * kt + 1]) : "v"(p2), "v"(p3));
                }
                lrun[bd] = ls;
                u32x4v w0 = {uu[0], uu[1], uu[2], uu[3]};   // keys (kt0,kt1) -> MFMA k 0..31
                u32x4v w1 = {uu[4], uu[5], uu[6], uu[7]};   // keys (kt2,kt3) -> MFMA k 32..63
                pa[bd][0] = __builtin_bit_cast(bf16x8, w0);
                pa[bd][1] = __builtin_bit_cast(bf16x8, w1);
            }

            // O += P V (Vs holds key-permuted Vt, so fragments line up)
            #pragma unroll
            for (int dt = 0; dt < 4; ++dt) {
                bf16x8 vb0 = *(const bf16x8*)&Vs[h2][(dt * 16 + c) * 64 + (g ^ c7) * 8];
                bf16x8 vb1 = *(const bf16x8*)&Vs[h2][(dt * 16 + c) * 64 + ((4 + g) ^ c7) * 8];
                #pragma unroll
                for (int bd = 0; bd < 2; ++bd) {
                    oac[bd][dt] = __builtin_amdgcn_mfma_f32_16x16x32_bf16(pa[bd][0], vb0, oac[bd][dt], 0, 0, 0);
                    oac[bd][dt] = __builtin_amdgcn_mfma_f32_16x16x32_bf16(pa[bd][1], vb1, oac[bd][dt], 0, 0, 0);
                }
            }

            __syncthreads();                     // drain (hidden) + buffer handoff
        }
    }

    #pragma unroll
    for (int bd = 0; bd < 2; ++bd) {
        float v = lrun[bd];
        v += __shfl_xor(v, 16);
        v += __shfl_xor(v, 32);
        lrun[bd] = v;
    }
    #pragma unroll
    for (int bd = 0; bd < 2; ++bd) {
        unsigned short* Op = O + (size_t)(b * SEQ + qw + bd * 16) * EMB + h * HD;
        #pragma unroll
        for (int r = 0; r < 4; ++r) {
            float linv = 1.0f / __shfl(lrun[bd], 4 * g + r);
            #pragma unroll
            for (int dt = 0; dt < 4; ++dt)
                Op[(size_t)(4 * g + r) * EMB + dt * 16 + c] = f2bf(oac[bd][dt][r] * linv);
        }
    }
}

} // anonymous namespace

extern "C" void kernel_launch(void* const* d_in, const int* in_sizes, int n_in,
                              void* d_out, int out_size, void* d_ws, size_t ws_size,
                              hipStream_t stream)
{
    const float* dec = (const float*)d_in[0];
    const float* enc = (const float*)d_in[1];
    const float* Wq  = (const float*)d_in[2];
    const float* Wk  = (const float*)d_in[3];
    const float* Wv  = (const float*)d_in[4];
    const float* Wo  = (const float*)d_in[5];
    const float* bo  = (const float*)d_in[6];
    float* out = (float*)d_out;

    const size_t BIG = (size_t)MTOT * EMB;     // 8M elems
    const size_t SML = (size_t)EMB * EMB;      // 1M elems
    unsigned short* decb = (unsigned short*)d_ws;
    unsigned short* encb = decb + BIG;
    unsigned short* WqT  = encb + BIG;         // Wq,Wk,Wv,Wo transposed, contiguous
    unsigned short* WoT  = WqT + 3 * SML;
    unsigned short* Qb   = WqT + 4 * SML;
    unsigned short* KVb  = Qb + BIG;           // [8192][2048] fused K|V
    unsigned short* Vtg  = KVb + 2 * BIG;
    unsigned short* Ob   = Vtg + BIG;          // total 120 MB

    dim3 blk(256);

    conv_bf16<<<dim3((unsigned)(BIG / 4 / 256), 2), blk, 0, stream>>>(
        dec, enc, decb, encb, (int)(BIG / 4));

    wtrans<<<dim3(16, 16, 4), blk, 0, stream>>>(Wq, Wk, Wv, Wo, WqT, 0.125f * LOG2E);

    // fused Q | K | V projections: 24 n-tiles x 64 m-tiles = 1536 blocks
    proj_fused<<<dim3(24, MTOT / 128), blk, 0, stream>>>(decb, encb, WqT, Qb, KVb);

    vtrans<<<dim3(SEQ / 64, BATCH * NH), blk, 0, stream>>>(KVb + EMB, Vtg);

    attn<<<dim3(SEQ / 128, BATCH * NH), blk, 0, stream>>>(Qb, KVb, Vtg, Ob);

    proj_out<<<dim3(EMB / 128, MTOT / 128), blk, 0, stream>>>(Ob, WoT, bo, out);
}

// Round 2
// 308.549 us; speedup vs baseline: 1.0768x; 1.0499x over previous
//
#include <hip/hip_runtime.h>
#include <hip/hip_bf16.h>

namespace {

typedef __attribute__((ext_vector_type(8))) short bf16x8;   // 8 bf16 = 4 VGPRs
typedef __attribute__((ext_vector_type(4))) float f32x4;
typedef __attribute__((ext_vector_type(4))) unsigned u32x4v;

constexpr int BATCH = 4;
constexpr int SEQ   = 2048;
constexpr int EMB   = 1024;
constexpr int NH    = 16;
constexpr int HD    = 64;
constexpr int MTOT  = BATCH * SEQ;           // 8192
constexpr int KVW   = 2 * EMB;               // fused K|V row width (2048)
constexpr float LOG2E = 1.44269504088896f;
constexpr float SOFTMAX_C = 16.0f;           // static max substitute (log2 units)

__device__ __forceinline__ unsigned short f2bf(float x) {
    unsigned int u = __float_as_uint(x);
    u += 0x7fffu + ((u >> 16) & 1u);         // round-to-nearest-even
    return (unsigned short)(u >> 16);
}

// async global->LDS, 16B per lane; LDS dest must be wave-uniform base + lane*16
__device__ __forceinline__ void gl_lds16(const void* g, void* l) {
    __builtin_amdgcn_global_load_lds(
        (const __attribute__((address_space(1))) unsigned int*)g,
        (__attribute__((address_space(3))) unsigned int*)l, 16, 0, 0);
}

// ---------------------------------------------------------------------------
// fp32 -> bf16 for dec (y=0) and enc (y=1) in one launch
// ---------------------------------------------------------------------------
__global__ __launch_bounds__(256)
void conv_bf16(const float* __restrict__ dec, const float* __restrict__ enc,
               unsigned short* __restrict__ decb, unsigned short* __restrict__ encb,
               int n4)
{
    int i = blockIdx.x * 256 + threadIdx.x;
    if (i >= n4) return;
    const float* src = blockIdx.y ? enc : dec;
    unsigned short* dst = blockIdx.y ? encb : decb;
    float4 v = ((const float4*)src)[i];
    ushort4 o;
    o.x = f2bf(v.x); o.y = f2bf(v.y); o.z = f2bf(v.z); o.w = f2bf(v.w);
    ((ushort4*)dst)[i] = o;
}

// ---------------------------------------------------------------------------
// All four weights: W[K][N] fp32 -> Wt[N][K] bf16 (×scale for z=0).
// ---------------------------------------------------------------------------
__global__ __launch_bounds__(256)
void wtrans(const float* __restrict__ W0, const float* __restrict__ W1,
            const float* __restrict__ W2, const float* __restrict__ W3,
            unsigned short* __restrict__ WtBase, float qscale)
{
    __shared__ __align__(16) unsigned short Ts[64][65];
    const int tid = threadIdx.x;
    const int z = blockIdx.z;
    const float* W = (z == 0) ? W0 : (z == 1) ? W1 : (z == 2) ? W2 : W3;
    unsigned short* Wt = WtBase + (size_t)z * EMB * EMB;
    const float scale = (z == 0) ? qscale : 1.0f;
    const int n0 = blockIdx.x * 64, k0 = blockIdx.y * 64;
    #pragma unroll
    for (int i = 0; i < 4; ++i) {
        int id = tid + i * 256;
        int r = id >> 4, q = id & 15;
        float4 v = *(const float4*)&W[(size_t)(k0 + r) * EMB + n0 + q * 4];
        Ts[q * 4 + 0][r] = f2bf(v.x * scale);
        Ts[q * 4 + 1][r] = f2bf(v.y * scale);
        Ts[q * 4 + 2][r] = f2bf(v.z * scale);
        Ts[q * 4 + 3][r] = f2bf(v.w * scale);
    }
    __syncthreads();
    #pragma unroll
    for (int i = 0; i < 4; ++i) {
        int id = tid + i * 256;
        int rn = id >> 4, q = id & 15;
        ushort4 o;
        o.x = Ts[rn][q * 4 + 0]; o.y = Ts[rn][q * 4 + 1];
        o.z = Ts[rn][q * 4 + 2]; o.w = Ts[rn][q * 4 + 3];
        *(ushort4*)&Wt[(size_t)(n0 + rn) * EMB + k0 + q * 4] = o;
    }
}

// ---------------------------------------------------------------------------
// V (cols 1024.. of KVb, row stride KVW) -> Vt[(b*16+h)*64 + d][S] bf16.
// KEY PERMUTATION: within each 32-key group, 4-key chunks are stored in order
// [0,4,1,5,2,6,3,7] so the attn PV A-fragment built in-register from the S^T
// output matches the B-operand k-slot mapping with no cross-lane movement.
// ---------------------------------------------------------------------------
__global__ __launch_bounds__(256)
void vtrans(const unsigned short* __restrict__ V, unsigned short* __restrict__ Vt)
{
    __shared__ __align__(16) unsigned short Ts[64][72];
    const int tid = threadIdx.x;
    const int s0 = blockIdx.x * 64;
    const int bh = blockIdx.y, b = bh >> 4, h = bh & 15;
    #pragma unroll
    for (int it = 0; it < 2; ++it) {
        int id = tid + it * 256;
        int r = id >> 3, seg = id & 7;
        uint4 v = *(const uint4*)&V[(size_t)(b * SEQ + s0 + r) * KVW + h * HD + seg * 8];
        const unsigned short* pv = (const unsigned short*)&v;
        #pragma unroll
        for (int j = 0; j < 8; ++j) Ts[seg * 8 + j][r] = pv[j];
    }
    __syncthreads();
    #pragma unroll
    for (int it = 0; it < 2; ++it) {
        int id = tid + it * 256;
        int d = id >> 3, sg = id & 7;
        int base = (sg >> 2) * 32 + (sg & 3) * 4;
        uint2 wlo = *(const uint2*)&Ts[d][base];
        uint2 whi = *(const uint2*)&Ts[d][base + 16];
        uint4 w;
        w.x = wlo.x; w.y = wlo.y; w.z = whi.x; w.w = whi.y;
        *(uint4*)&Vt[((size_t)bh * HD + d) * SEQ + s0 + sg * 8] = w;
    }
}

// ---------------------------------------------------------------------------
// Pipelined GEMM body: C[M,N] = A[M,K] @ Bt[N,K]^T (+bias). 128x128 tile,
// BK=32, DOUBLE-buffered LDS + global_load_lds.
// ---------------------------------------------------------------------------
template<bool OUT_BF16, bool BIAS>
__device__ __forceinline__
void gemm_body(const unsigned short* __restrict__ A, const unsigned short* __restrict__ Bt,
               const float* __restrict__ bias, void* __restrict__ Cout,
               int m0, int n0, int N, int Kd)
{
    __shared__ __align__(16) unsigned short As[2][128 * 32];
    __shared__ __align__(16) unsigned short Bs[2][128 * 32];
    const int tid  = threadIdx.x;
    const int lane = tid & 63, wave = tid >> 6;
    const int g = lane >> 4, c = lane & 15;
    const int wm = (wave & 1) * 64, wn = (wave >> 1) * 64;

    const int r0 = tid >> 2, s = tid & 3;
    const int sg = s ^ ((r0 + (r0 >> 2)) & 3);
    const unsigned short* ga0 = A  + (size_t)(m0 + r0)      * Kd + sg * 8;
    const unsigned short* ga1 = A  + (size_t)(m0 + r0 + 64) * Kd + sg * 8;
    const unsigned short* gb0 = Bt + (size_t)(n0 + r0)      * Kd + sg * 8;
    const unsigned short* gb1 = Bt + (size_t)(n0 + r0 + 64) * Kd + sg * 8;
    const int lo0 = tid * 8, lo1 = (256 + tid) * 8;

    const int cs = (c + (c >> 2)) & 3;

    f32x4 acc[4][4];
    #pragma unroll
    for (int i = 0; i < 4; ++i)
        #pragma unroll
        for (int j = 0; j < 4; ++j) acc[i][j] = (f32x4)0.0f;

    // prologue: tile 0 -> buf0
    gl_lds16(ga0, &As[0][lo0]); gl_lds16(ga1, &As[0][lo1]);
    gl_lds16(gb0, &Bs[0][lo0]); gl_lds16(gb1, &Bs[0][lo1]);
    ga0 += 32; ga1 += 32; gb0 += 32; gb1 += 32;
    __syncthreads();

    const int KT = Kd / 32;                      // even
    for (int kt = 0; kt < KT; kt += 2) {
        #pragma unroll
        for (int h2 = 0; h2 < 2; ++h2) {         // h2 = buffer parity (constant)
            const int k = kt + h2;
            if (k + 1 < KT) {                    // issue next tile early (async)
                gl_lds16(ga0, &As[h2 ^ 1][lo0]); gl_lds16(ga1, &As[h2 ^ 1][lo1]);
                gl_lds16(gb0, &Bs[h2 ^ 1][lo0]); gl_lds16(gb1, &Bs[h2 ^ 1][lo1]);
                ga0 += 32; ga1 += 32; gb0 += 32; gb1 += 32;
            }
            bf16x8 af[4], bfr[4];
            #pragma unroll
            for (int mt = 0; mt < 4; ++mt)
                af[mt]  = *(const bf16x8*)&As[h2][(wm + mt * 16 + c) * 32 + (g ^ cs) * 8];
            #pragma unroll
            for (int nt = 0; nt < 4; ++nt)
                bfr[nt] = *(const bf16x8*)&Bs[h2][(wn + nt * 16 + c) * 32 + (g ^ cs) * 8];
            #pragma unroll
            for (int mt = 0; mt < 4; ++mt)
                #pragma unroll
                for (int nt = 0; nt < 4; ++nt)
                    acc[mt][nt] = __builtin_amdgcn_mfma_f32_16x16x32_bf16(af[mt], bfr[nt], acc[mt][nt], 0, 0, 0);
            __syncthreads();                     // drain lands post-compute
        }
    }

    #pragma unroll
    for (int mt = 0; mt < 4; ++mt) {
        #pragma unroll
        for (int nt = 0; nt < 4; ++nt) {
            int n = n0 + wn + nt * 16 + c;
            float bv = BIAS ? bias[n] : 0.0f;
            #pragma unroll
            for (int r = 0; r < 4; ++r) {
                int m = m0 + wm + mt * 16 + 4 * g + r;
                float v = acc[mt][nt][r] + bv;
                if (OUT_BF16) ((unsigned short*)Cout)[(size_t)m * N + n] = f2bf(v);
                else          ((float*)Cout)[(size_t)m * N + n] = v;
            }
        }
    }
}

// Fused Q + KV projections. XCD-aware remap: hw dispatch id (x-fastest) is
// round-robined over 8 XCDs; give each XCD a contiguous band of 8 m-tiles so
// its A working set is 2 MB (fits its private L2) instead of ~16 MB.
__global__ __launch_bounds__(256)
void proj_fused(const unsigned short* __restrict__ decb, const unsigned short* __restrict__ encb,
                const unsigned short* __restrict__ WtBase,
                unsigned short* __restrict__ Qb, unsigned short* __restrict__ KVb)
{
    const int fid = blockIdx.y * 24 + blockIdx.x;   // 0..1535, hw dispatch order
    const int xcd = fid & 7, idx = fid >> 3;        // idx: 0..191
    const int mt  = (xcd << 3) | (idx / 24);        // 0..63  (8 m-tiles per XCD)
    const int nt  = idx % 24;
    const int m0  = mt * 128;
    if (nt < 8) {
        gemm_body<true, false>(decb, WtBase, nullptr, Qb, m0, nt * 128, EMB, EMB);
    } else {
        gemm_body<true, false>(encb, WtBase + (size_t)EMB * EMB, nullptr, KVb,
                               m0, (nt - 8) * 128, KVW, EMB);
    }
}

// Out projection (fp32 out + bias), same XCD-band remap (512 blocks).
__global__ __launch_bounds__(256)
void proj_out(const unsigned short* __restrict__ Ob, const unsigned short* __restrict__ WoT,
              const float* __restrict__ bo, float* __restrict__ out)
{
    const int fid = blockIdx.y * 8 + blockIdx.x;    // 0..511
    const int xcd = fid & 7, idx = fid >> 3;        // idx: 0..63
    const int mt  = (xcd << 3) | (idx >> 3);
    const int nt  = idx & 7;
    gemm_body<false, true>(Ob, WoT, bo, out, mt * 128, nt * 128, EMB, EMB);
}

// ---------------------------------------------------------------------------
// MFMA flash attention, S^T formulation, static max folded into MFMA C-init.
// P stays in registers (permuted k-map, see vtrans). XCD-aware block remap:
// all 16 q-blocks of one (b,h) land on ONE XCD, so each XCD's concurrent K/V
// working set is 8 heads x 512 KB = 4 MB = its L2 (was: all 64 heads, 32 MB,
// thrash -> 3x HBM refetch and HBM-latency barrier drains).
// ---------------------------------------------------------------------------
__global__ __launch_bounds__(256)
void attn(const unsigned short* __restrict__ Q, const unsigned short* __restrict__ KV,
          const unsigned short* __restrict__ Vt, unsigned short* __restrict__ O)
{
    __shared__ __align__(16) unsigned short Ks[2][64 * 64];  // [key][d], seg^(row&7)
    __shared__ __align__(16) unsigned short Vs[2][64 * 64];  // [d][key], seg^(row&7)

    const int tid  = threadIdx.x;
    const int lane = tid & 63, wave = tid >> 6;
    const int g = lane >> 4, c = lane & 15, c7 = c & 7;

    // XCD-aware bijective remap of the 1024 blocks (16 q-tiles x 64 bh)
    const int fid  = blockIdx.y * 16 + blockIdx.x;  // hw dispatch order (x fastest)
    const int xcd  = fid & 7, idx = fid >> 3;       // idx: 0..127 within XCD
    const int bh   = (xcd << 3) | (idx >> 4);       // 8 heads per XCD
    const int qblk = idx & 15;
    const int b = bh >> 4, h = bh & 15;
    const int qw = qblk * 128 + wave * 32;

    const unsigned short* Qp0 = Q + (size_t)(b * SEQ + qw + c) * EMB + h * HD;
    const unsigned short* Qp1 = Qp0 + (size_t)16 * EMB;
    bf16x8 qb[2][2];
    qb[0][0] = *(const bf16x8*)(Qp0 + g * 8);
    qb[0][1] = *(const bf16x8*)(Qp0 + 32 + g * 8);
    qb[1][0] = *(const bf16x8*)(Qp1 + g * 8);
    qb[1][1] = *(const bf16x8*)(Qp1 + 32 + g * 8);

    const int r0 = tid >> 3, s8 = tid & 7;
    const int sg = s8 ^ (r0 & 7);
    const unsigned short* gK0 = KV + ((size_t)b * SEQ + r0) * KVW + h * HD + sg * 8;
    const unsigned short* gK1 = gK0 + (size_t)32 * KVW;
    const unsigned short* gV0 = Vt + (size_t)bh * HD * SEQ + (size_t)r0 * SEQ + sg * 8;
    const unsigned short* gV1 = gV0 + (size_t)32 * SEQ;
    const int lo0 = tid * 8, lo1 = (256 + tid) * 8;

    f32x4 oac[2][4];
    #pragma unroll
    for (int bd = 0; bd < 2; ++bd)
        #pragma unroll
        for (int dt = 0; dt < 4; ++dt) oac[bd][dt] = (f32x4)0.0f;
    float lrun[2] = {0.0f, 0.0f};
    const f32x4 minit = {-SOFTMAX_C, -SOFTMAX_C, -SOFTMAX_C, -SOFTMAX_C};

    // prologue: tile 0 -> buf0
    gl_lds16(gK0, &Ks[0][lo0]); gl_lds16(gK1, &Ks[0][lo1]);
    gl_lds16(gV0, &Vs[0][lo0]); gl_lds16(gV1, &Vs[0][lo1]);
    gK0 += (size_t)64 * KVW; gK1 += (size_t)64 * KVW; gV0 += 64; gV1 += 64;
    __syncthreads();

    constexpr int T = SEQ / 64;                  // 32, even
    for (int t = 0; t < T; t += 2) {
        #pragma unroll
        for (int h2 = 0; h2 < 2; ++h2) {         // h2 = buffer parity (constant)
            const int tt = t + h2;
            if (tt + 1 < T) {                    // issue next K/V tile early
                gl_lds16(gK0, &Ks[h2 ^ 1][lo0]); gl_lds16(gK1, &Ks[h2 ^ 1][lo1]);
                gl_lds16(gV0, &Vs[h2 ^ 1][lo0]); gl_lds16(gV1, &Vs[h2 ^ 1][lo1]);
                gK0 += (size_t)64 * KVW; gK1 += (size_t)64 * KVW;
                gV0 += 64;               gV1 += 64;
            }

            // S^T = K Q^T, C-init = -C (softmax shift folded in)
            f32x4 st[2][4];
            __builtin_amdgcn_s_setprio(1);
            #pragma unroll
            for (int kt = 0; kt < 4; ++kt) {
                bf16x8 ka0 = *(const bf16x8*)&Ks[h2][(kt * 16 + c) * 64 + (g ^ c7) * 8];
                bf16x8 ka1 = *(const bf16x8*)&Ks[h2][(kt * 16 + c) * 64 + ((4 + g) ^ c7) * 8];
                #pragma unroll
                for (int bd = 0; bd < 2; ++bd) {
                    st[bd][kt] = __builtin_amdgcn_mfma_f32_16x16x32_bf16(ka0, qb[bd][0], minit, 0, 0, 0);
                    st[bd][kt] = __builtin_amdgcn_mfma_f32_16x16x32_bf16(ka1, qb[bd][1], st[bd][kt], 0, 0, 0);
                }
            }
            __builtin_amdgcn_s_setprio(0);

            // p = exp2(st); accumulate l; pack in-register (v_cvt_pk_bf16_f32).
            bf16x8 pa[2][2];
            #pragma unroll
            for (int bd = 0; bd < 2; ++bd) {
                float ls = lrun[bd];
                unsigned uu[8];
                #pragma unroll
                for (int kt = 0; kt < 4; ++kt) {
                    float p0 = __builtin_amdgcn_exp2f(st[bd][kt][0]);
                    float p1 = __builtin_amdgcn_exp2f(st[bd][kt][1]);
                    float p2 = __builtin_amdgcn_exp2f(st[bd][kt][2]);
                    float p3 = __builtin_amdgcn_exp2f(st[bd][kt][3]);
                    ls += (p0 + p1) + (p2 + p3);
                    asm("v_cvt_pk_bf16_f32 %0, %1, %2" : "=v"(uu[2 * kt])     : "v"(p0), "v"(p1));
                    asm("v_cvt_pk_bf16_f32 %0, %1, %2" : "=v"(uu[2 * kt + 1]) : "v"(p2), "v"(p3));
                }
                lrun[bd] = ls;
                u32x4v w0 = {uu[0], uu[1], uu[2], uu[3]};   // keys (kt0,kt1) -> MFMA k 0..31
                u32x4v w1 = {uu[4], uu[5], uu[6], uu[7]};   // keys (kt2,kt3) -> MFMA k 32..63
                pa[bd][0] = __builtin_bit_cast(bf16x8, w0);
                pa[bd][1] = __builtin_bit_cast(bf16x8, w1);
            }

            // O += P V (Vs holds key-permuted Vt, so fragments line up)
            __builtin_amdgcn_s_setprio(1);
            #pragma unroll
            for (int dt = 0; dt < 4; ++dt) {
                bf16x8 vb0 = *(const bf16x8*)&Vs[h2][(dt * 16 + c) * 64 + (g ^ c7) * 8];
                bf16x8 vb1 = *(const bf16x8*)&Vs[h2][(dt * 16 + c) * 64 + ((4 + g) ^ c7) * 8];
                #pragma unroll
                for (int bd = 0; bd < 2; ++bd) {
                    oac[bd][dt] = __builtin_amdgcn_mfma_f32_16x16x32_bf16(pa[bd][0], vb0, oac[bd][dt], 0, 0, 0);
                    oac[bd][dt] = __builtin_amdgcn_mfma_f32_16x16x32_bf16(pa[bd][1], vb1, oac[bd][dt], 0, 0, 0);
                }
            }
            __builtin_amdgcn_s_setprio(0);

            __syncthreads();                     // drain (hidden) + buffer handoff
        }
    }

    #pragma unroll
    for (int bd = 0; bd < 2; ++bd) {
        float v = lrun[bd];
        v += __shfl_xor(v, 16);
        v += __shfl_xor(v, 32);
        lrun[bd] = v;
    }
    #pragma unroll
    for (int bd = 0; bd < 2; ++bd) {
        unsigned short* Op = O + (size_t)(b * SEQ + qw + bd * 16) * EMB + h * HD;
        #pragma unroll
        for (int r = 0; r < 4; ++r) {
            float linv = 1.0f / __shfl(lrun[bd], 4 * g + r);
            #pragma unroll
            for (int dt = 0; dt < 4; ++dt)
                Op[(size_t)(4 * g + r) * EMB + dt * 16 + c] = f2bf(oac[bd][dt][r] * linv);
        }
    }
}

} // anonymous namespace

extern "C" void kernel_launch(void* const* d_in, const int* in_sizes, int n_in,
                              void* d_out, int out_size, void* d_ws, size_t ws_size,
                              hipStream_t stream)
{
    const float* dec = (const float*)d_in[0];
    const float* enc = (const float*)d_in[1];
    const float* Wq  = (const float*)d_in[2];
    const float* Wk  = (const float*)d_in[3];
    const float* Wv  = (const float*)d_in[4];
    const float* Wo  = (const float*)d_in[5];
    const float* bo  = (const float*)d_in[6];
    float* out = (float*)d_out;

    const size_t BIG = (size_t)MTOT * EMB;     // 8M elems
    const size_t SML = (size_t)EMB * EMB;      // 1M elems
    unsigned short* decb = (unsigned short*)d_ws;
    unsigned short* encb = decb + BIG;
    unsigned short* WqT  = encb + BIG;         // Wq,Wk,Wv,Wo transposed, contiguous
    unsigned short* WoT  = WqT + 3 * SML;
    unsigned short* Qb   = WqT + 4 * SML;
    unsigned short* KVb  = Qb + BIG;           // [8192][2048] fused K|V
    unsigned short* Vtg  = KVb + 2 * BIG;
    unsigned short* Ob   = Vtg + BIG;          // total 120 MB

    dim3 blk(256);

    conv_bf16<<<dim3((unsigned)(BIG / 4 / 256), 2), blk, 0, stream>>>(
        dec, enc, decb, encb, (int)(BIG / 4));

    wtrans<<<dim3(16, 16, 4), blk, 0, stream>>>(Wq, Wk, Wv, Wo, WqT, 0.125f * LOG2E);

    // fused Q | K | V projections: 24 n-tiles x 64 m-tiles = 1536 blocks
    proj_fused<<<dim3(24, MTOT / 128), blk, 0, stream>>>(decb, encb, WqT, Qb, KVb);

    vtrans<<<dim3(SEQ / 64, BATCH * NH), blk, 0, stream>>>(KVb + EMB, Vtg);

    attn<<<dim3(SEQ / 128, BATCH * NH), blk, 0, stream>>>(Qb, KVb, Vtg, Ob);

    proj_out<<<dim3(EMB / 128, MTOT / 128), blk, 0, stream>>>(Ob, WoT, bo, out);
}